// Round 7
// baseline (346.139 us; speedup 1.0000x reference)
//
#include <hip/hip_runtime.h>

typedef _Float16 f16;
typedef __attribute__((ext_vector_type(4))) _Float16 f16x4;
typedef __attribute__((ext_vector_type(8))) _Float16 f16x8;
typedef __attribute__((ext_vector_type(4))) float f32x4;

#define B_ 4
#define N_ 2048
#define D_ 1024

#define FENCE asm volatile("" ::: "memory")

// ---------------------------------------------------------------- cast fp32->fp16 + rowsum zeroing
__global__ __launch_bounds__(256) void k_cast_all(const float4* __restrict__ x,
                                                  const float4* __restrict__ wq,
                                                  const float4* __restrict__ wk,
                                                  const float4* __restrict__ wv,
                                                  f16x4* __restrict__ xo,
                                                  f16x4* __restrict__ wqo,
                                                  f16x4* __restrict__ wko,
                                                  f16x4* __restrict__ wvo,
                                                  float* __restrict__ rowsum) {
  int b = blockIdx.x;
  if (b >= 11264) {                      // 32 blocks zero the 8192-float rowsum
    rowsum[(b - 11264) * 256 + threadIdx.x] = 0.f;
    return;
  }
  const float4* in;
  f16x4* out;
  int idx;
  if (b < 8192)       { in = x;  out = xo;  idx = b * 256 + threadIdx.x; }
  else if (b < 9216)  { in = wq; out = wqo; idx = (b - 8192) * 256 + threadIdx.x; }
  else if (b < 10240) { in = wk; out = wko; idx = (b - 9216) * 256 + threadIdx.x; }
  else                { in = wv; out = wvo; idx = (b - 10240) * 256 + threadIdx.x; }
  float4 v = in[idx];
  f16x4 o = { (_Float16)v.x, (_Float16)v.y, (_Float16)v.z, (_Float16)v.w };
  out[idx] = o;
}

// ---------------------------------------------------------------- staging (proven-clean geometry)
// Half-tile = 128 rows x 128 B (BK=64 f16). 16B chunks XOR-swizzled by (row&7)
// on the GLOBAL source (LDS dest stays linear per global_load_lds constraint);
// reads apply the same XOR -> both-sides involution. 2 loads/thread (2/wave vmcnt).
__device__ __forceinline__ void stage_half(const char* g0, int ldB, int kByte,
                                           char* slot, int tid) {
#pragma unroll
  for (int r = 0; r < 2; ++r) {
    int lin = r * 8192 + tid * 16;
    int row = lin >> 7;
    int lch = ((lin >> 4) & 7) ^ (row & 7);
    const char* g = g0 + (long)row * ldB + kByte + lch * 16;
    char* l = slot + r * 8192 + ((tid >> 6) << 10);   // wave-uniform base; HW adds lane*16
    __builtin_amdgcn_global_load_lds(
        (const __attribute__((address_space(1))) unsigned int*)g,
        (__attribute__((address_space(3))) unsigned int*)l, 16, 0, 0);
  }
}

// ---------------------------------------------------------------- fragment read / MFMA macros
#define RD_A(dst, base)                                                          \
  _Pragma("unroll") for (int i_ = 0; i_ < 4; ++i_) {                             \
    int rA_ = wm * 64 + i_ * 16 + l16;                                           \
    _Pragma("unroll") for (int k_ = 0; k_ < 2; ++k_)                             \
      dst[i_][k_] = *(const f16x8*)((base) + rA_ * 128 +                         \
                                    ((((k_ << 2) | quad) ^ l7) << 4));           \
  }
#define RD_B(dst, base)                                                          \
  _Pragma("unroll") for (int j_ = 0; j_ < 2; ++j_) {                             \
    int rB_ = wn * 32 + j_ * 16 + l16;                                           \
    _Pragma("unroll") for (int k_ = 0; k_ < 2; ++k_)                             \
      dst[j_][k_] = *(const f16x8*)((base) + rB_ * 128 +                         \
                                    ((((k_ << 2) | quad) ^ l7) << 4));           \
  }
#define MFMA8(Av, Bv, BH)                                                        \
  __builtin_amdgcn_s_setprio(1);                                                 \
  _Pragma("unroll") for (int i_ = 0; i_ < 4; ++i_)                               \
  _Pragma("unroll") for (int j_ = 0; j_ < 2; ++j_)                               \
  _Pragma("unroll") for (int k_ = 0; k_ < 2; ++k_)                               \
    acc[i_][BH][j_] = __builtin_amdgcn_mfma_f32_16x16x32_f16(                    \
        Av[i_][k_], Bv[j_][k_], acc[i_][BH][j_], 0, 0, 0);                       \
  __builtin_amdgcn_s_setprio(0);
#define MFMA16(Av, Bv, AH, BH)                                                   \
  __builtin_amdgcn_s_setprio(1);                                                 \
  _Pragma("unroll") for (int i_ = 0; i_ < 4; ++i_)                               \
  _Pragma("unroll") for (int j_ = 0; j_ < 2; ++j_)                               \
  _Pragma("unroll") for (int k_ = 0; k_ < 2; ++k_)                               \
    acc[AH][i_][BH][j_] = __builtin_amdgcn_mfma_f32_16x16x32_f16(                \
        Av[i_][k_], Bv[j_][k_], acc[AH][i_][BH][j_], 0, 0, 0);                   \
  __builtin_amdgcn_s_setprio(0);

// ---------------------------------------------------------------- 256x256 NT GEMM v3 (m201-faithful)
// 8 waves, wave tile 128x64, quadrants (Ah,Bh). 8-phase iteration over 2 K-tiles,
// FIXED buffer parity (even tiles buf0, odd buf1). Snake quadrant order:
//  f1:t0(A0,B0) f2:t0(A1,B0) f3:t0(A1,B1) f4:t0(A0,B1)
//  f5:t1(A1,B0) f6:t1(A0,B0) f7:t1(A0,B1) f8:t1(A1,B1)
// Reads ONE PHASE AHEAD into the register not used by this phase's MFMA:
//  f1:a1<-A1(t0) f2:bY<-B1(t0) f3:bX<-B0(t1) f4:a1<-A1(t1)
//  f5:a0<-A0(t1) f6:bY<-B1(t1) f7:bX<-B0(t0+2) f8:a0<-A0(t0+2)
// Stages one half/phase, 6-PHASE LANDING SLACK (~4000cy), slot consumed >=2 barriers
// before its stage-issue:
//  f1:B0(t0+2) f2:A0(t0+2) f3:A1(t0+2) f4:B1(t0+2)
//  f5:B0(t1+2) f6:A1(t1+2) f7:A0(t1+2) f8:B1(t1+2)
// FIFO ledger (2 loads/half): uniform vmcnt(10) retires EXACTLY the half read this
// phase (audited: prologue, steady, tail 10/8/6/4/2/0). lgkmcnt(0) folded into each
// wait closes the stage-vs-outstanding-read race with a SINGLE barrier per phase.
__device__ __forceinline__ void gemm256(const char* gA, int ldaB,
                                        const char* gB, int ldbB,
                                        int nK, char* lds, f32x4 acc[2][4][2][2]) {
  const int tid = threadIdx.x;
  const int lane = tid & 63, wave = tid >> 6;
  const int wm = wave >> 2, wn = wave & 3;
  const int quad = lane >> 4, l16 = lane & 15;
  const int l7 = l16 & 7;
  const char* gA1 = gA + (long)128 * ldaB;
  const char* gB1 = gB + (long)128 * ldbB;
  char* const A00 = lds;                 // A-half0, even tiles
  char* const A10 = lds + 16384;         // A-half1, even
  char* const A01 = lds + 32768;         // A-half0, odd
  char* const A11 = lds + 49152;         // A-half1, odd
  char* const B00 = lds + 65536;
  char* const B10 = lds + 81920;
  char* const B01 = lds + 98304;
  char* const B11 = lds + 114688;
  f16x8 a0[4][2], a1[4][2], bX[2][2], bY[2][2];
  // prologue: stage both tiles' 8 halves in FIFO order matching the steady queue
  stage_half(gB,  ldbB, 0, B00, tid);    // B0(0)
  stage_half(gA,  ldaB, 0, A00, tid);    // A0(0)
  stage_half(gA1, ldaB, 0, A10, tid);    // A1(0)
  stage_half(gB1, ldbB, 0, B10, tid);    // B1(0)
  stage_half(gB,  ldbB, 128, B01, tid);  // B0(1)
  stage_half(gA1, ldaB, 128, A11, tid);  // A1(1)
  stage_half(gA,  ldaB, 128, A01, tid);  // A0(1)
  stage_half(gB1, ldbB, 128, B11, tid);  // B1(1)
  asm volatile("s_waitcnt vmcnt(12)" ::: "memory");  // B0(0),A0(0) landed
  __builtin_amdgcn_s_barrier(); FENCE;
  RD_B(bX, B00); RD_A(a0, A00);
  const int nIt = nK >> 1;
  for (int u = 0; u < nIt; ++u) {
    const bool st = (u + 1 < nIt);
    const int kB0 = (u * 2 + 2) << 7;
    const int kB1 = (u * 2 + 3) << 7;
    // f1 ------------------------------------------------------ t0:(A0,B0)
    asm volatile("s_waitcnt vmcnt(10) lgkmcnt(0)" ::: "memory");
    __builtin_amdgcn_s_barrier(); FENCE;
    if (st) stage_half(gB, ldbB, kB0, B00, tid);
    RD_A(a1, A10);
    MFMA16(a0, bX, 0, 0);
    // f2 ------------------------------------------------------ t0:(A1,B0)
    if (st) asm volatile("s_waitcnt vmcnt(10) lgkmcnt(0)" ::: "memory");
    else    asm volatile("s_waitcnt vmcnt(8) lgkmcnt(0)" ::: "memory");
    __builtin_amdgcn_s_barrier(); FENCE;
    if (st) stage_half(gA, ldaB, kB0, A00, tid);
    RD_B(bY, B10);
    MFMA16(a1, bX, 1, 0);
    // f3 ------------------------------------------------------ t0:(A1,B1)
    if (st) asm volatile("s_waitcnt vmcnt(10) lgkmcnt(0)" ::: "memory");
    else    asm volatile("s_waitcnt vmcnt(6) lgkmcnt(0)" ::: "memory");
    __builtin_amdgcn_s_barrier(); FENCE;
    if (st) stage_half(gA1, ldaB, kB0, A10, tid);
    RD_B(bX, B01);
    MFMA16(a1, bY, 1, 1);
    // f4 ------------------------------------------------------ t0:(A0,B1)
    if (st) asm volatile("s_waitcnt vmcnt(10) lgkmcnt(0)" ::: "memory");
    else    asm volatile("s_waitcnt vmcnt(4) lgkmcnt(0)" ::: "memory");
    __builtin_amdgcn_s_barrier(); FENCE;
    if (st) stage_half(gB1, ldbB, kB0, B10, tid);
    RD_A(a1, A11);
    MFMA16(a0, bY, 0, 1);
    // f5 ------------------------------------------------------ t1:(A1,B0)
    if (st) asm volatile("s_waitcnt vmcnt(10) lgkmcnt(0)" ::: "memory");
    else    asm volatile("s_waitcnt vmcnt(2) lgkmcnt(0)" ::: "memory");
    __builtin_amdgcn_s_barrier(); FENCE;
    if (st) stage_half(gB, ldbB, kB1, B01, tid);
    RD_A(a0, A01);
    MFMA16(a1, bX, 1, 0);
    // f6 ------------------------------------------------------ t1:(A0,B0)
    if (st) asm volatile("s_waitcnt vmcnt(10) lgkmcnt(0)" ::: "memory");
    else    asm volatile("s_waitcnt vmcnt(0) lgkmcnt(0)" ::: "memory");
    __builtin_amdgcn_s_barrier(); FENCE;
    if (st) stage_half(gA1, ldaB, kB1, A11, tid);
    RD_B(bY, B11);
    MFMA16(a0, bX, 0, 0);
    // f7 ------------------------------------------------------ t1:(A0,B1)
    if (st) asm volatile("s_waitcnt vmcnt(10) lgkmcnt(0)" ::: "memory");
    __builtin_amdgcn_s_barrier(); FENCE;
    if (st) { stage_half(gA, ldaB, kB1, A01, tid); RD_B(bX, B00); }
    MFMA16(a0, bY, 0, 1);
    // f8 ------------------------------------------------------ t1:(A1,B1)
    if (st) asm volatile("s_waitcnt vmcnt(10) lgkmcnt(0)" ::: "memory");
    __builtin_amdgcn_s_barrier(); FENCE;
    if (st) { stage_half(gB1, ldbB, kB1, B11, tid); RD_A(a0, A00); }
    MFMA16(a1, bY, 1, 1);
  }
  asm volatile("s_waitcnt vmcnt(0) lgkmcnt(0)" ::: "memory");
  __builtin_amdgcn_s_barrier(); FENCE;
}

// ---------------------------------------------------------------- 128x256 DEEP-phase NT GEMM (k_out)
// 8 waves, wave 64x64; reads-one-phase-ahead, dbuf 48 KB x2. Validated R5 (unchanged).
#define D128_TILE(AC, B0C, AN, B0N, q) {                                         \
  char* Sc = lds + (q) * 49152;                                                  \
  char* Sn = lds + ((q) ^ 1) * 49152;                                            \
  const int kB = (t + 1) << 7;                                                   \
  stage_half(gA, ldaB, kB, Sn, tid);                                             \
  stage_half(gB, ldbB, kB, Sn + 16384, tid);                                     \
  asm volatile("s_waitcnt vmcnt(4)" ::: "memory");                               \
  __builtin_amdgcn_s_barrier(); FENCE;                                           \
  RD_B(b1, Sc + 32768);                                                          \
  MFMA8(AC, B0C, 0);                                                             \
  stage_half(gB1, ldbB, kB, Sn + 32768, tid);                                    \
  asm volatile("s_waitcnt vmcnt(2)" ::: "memory");                               \
  __builtin_amdgcn_s_barrier(); FENCE;                                           \
  RD_A(AN, Sn); RD_B(B0N, Sn + 16384);                                           \
  MFMA8(AC, b1, 1);                                                              \
}
#define D128_TAIL(AC, B0C, q) {                                                  \
  char* Sc = lds + (q) * 49152;                                                  \
  asm volatile("s_waitcnt vmcnt(0)" ::: "memory");                               \
  __builtin_amdgcn_s_barrier(); FENCE;                                           \
  RD_B(b1, Sc + 32768);                                                          \
  MFMA8(AC, B0C, 0);                                                             \
  MFMA8(AC, b1, 1);                                                              \
}

__device__ __forceinline__ void gemm_d128(const char* gA, int ldaB,
                                          const char* gB, int ldbB,
                                          int nK, char* lds, f32x4 acc[4][2][2]) {
  const int tid = threadIdx.x;
  const int lane = tid & 63, wave = tid >> 6;
  const int wm = wave >> 2, wn = wave & 3;
  const int quad = lane >> 4, l16 = lane & 15;
  const int l7 = l16 & 7;
  const char* gB1 = gB + (long)128 * ldbB;
  f16x8 aX[4][2], aY[4][2], b0X[2][2], b0Y[2][2], b1[2][2];
  stage_half(gA,  ldaB, 0, lds, tid);
  stage_half(gB,  ldbB, 0, lds + 16384, tid);
  stage_half(gB1, ldbB, 0, lds + 32768, tid);
  asm volatile("s_waitcnt vmcnt(2)" ::: "memory");   // A,B0 landed; B1 in flight
  __builtin_amdgcn_s_barrier(); FENCE;
  RD_A(aX, lds); RD_B(b0X, lds + 16384);
  for (int tb = 0; tb < nK - 2; tb += 2) {
    { const int t = tb;     D128_TILE(aX, b0X, aY, b0Y, 0) }
    { const int t = tb + 1; D128_TILE(aY, b0Y, aX, b0X, 1) }
  }
  { const int t = nK - 2;   D128_TILE(aX, b0X, aY, b0Y, 0) }
  D128_TAIL(aY, b0Y, 1)
  __builtin_amdgcn_s_barrier(); FENCE;   // all waves' frag reads done -> LDS reusable
}

// ---------------------------------------------------------------- fused QKV projection (+V transpose)
// Wide GEMM [8192, 3072] in 256x256 tiles -> 384 blocks (XCD row-bands for X L2 reuse).
__global__ __launch_bounds__(512, 2) void k_qkv(const f16* __restrict__ X,
                                                const f16* __restrict__ Wq,
                                                const f16* __restrict__ Wk,
                                                const f16* __restrict__ Wv,
                                                const float* __restrict__ bq,
                                                const float* __restrict__ bk,
                                                const float* __restrict__ bv,
                                                f16* __restrict__ Q, f16* __restrict__ Ko,
                                                f16* __restrict__ Vt) {
  __shared__ __align__(16) char lds[131072];
  int fid = blockIdx.x;
  int xcd = fid & 7, k = fid >> 3;          // k in [0,48)
  int rowt = xcd * 4 + (k & 3);             // 0..31
  int colt = k >> 2;                        // 0..11
  int tm = rowt * 256;
  int w = colt >> 2;                        // 0:Q 1:K 2:V
  int tn = (colt & 3) * 256;
  const f16* Wsel = (w == 0) ? Wq : (w == 1) ? Wk : Wv;
  f32x4 acc[2][4][2][2];
#pragma unroll
  for (int Ah = 0; Ah < 2; ++Ah)
#pragma unroll
    for (int i = 0; i < 4; ++i)
#pragma unroll
      for (int Bh = 0; Bh < 2; ++Bh)
#pragma unroll
        for (int jn = 0; jn < 2; ++jn) acc[Ah][i][Bh][jn] = (f32x4){0.f, 0.f, 0.f, 0.f};
  gemm256((const char*)(X + (long)tm * D_), D_ * 2,
          (const char*)(Wsel + (long)tn * D_), D_ * 2, D_ / 64, lds, acc);
  const int tid = threadIdx.x;
  const int lane = tid & 63, wave = tid >> 6;
  const int wm = wave >> 2, wn = wave & 3;
  const int quad = lane >> 4, l16 = lane & 15;
  if (w < 2) {
    const float* bias = w ? bk : bq;
    f16* outp = w ? Ko : Q;
#pragma unroll
    for (int Bh = 0; Bh < 2; ++Bh)
#pragma unroll
      for (int jn = 0; jn < 2; ++jn) {
        int col = tn + Bh * 128 + wn * 32 + jn * 16 + l16;
        float bb = bias[col];
#pragma unroll
        for (int Ah = 0; Ah < 2; ++Ah)
#pragma unroll
          for (int i = 0; i < 4; ++i) {
            int rbase = tm + Ah * 128 + wm * 64 + i * 16 + quad * 4;
#pragma unroll
            for (int r = 0; r < 4; ++r)
              outp[(long)(rbase + r) * D_ + col] = (_Float16)(acc[Ah][i][Bh][jn][r] + bb);
          }
      }
  } else {
    // V: transpose through LDS in 2 feature-passes of 128 (pass == Bh)
    int bidx = tm >> 11, ntok = tm & 2047;
    f16* VtB = Vt + (long)bidx * D_ * N_ + ntok;
    f16* ldsT = (f16*)lds;                  // 128 x 264 f16 = 67.6 KB
#pragma unroll
    for (int pass = 0; pass < 2; ++pass) {
      FENCE;
      __builtin_amdgcn_s_barrier();
      FENCE;
#pragma unroll
      for (int jn = 0; jn < 2; ++jn) {
        int fl = wn * 32 + jn * 16 + l16;             // local feature 0..127
        float bb = bv[tn + pass * 128 + fl];
#pragma unroll
        for (int Ah = 0; Ah < 2; ++Ah)
#pragma unroll
          for (int i = 0; i < 4; ++i) {
            int rl = Ah * 128 + wm * 64 + i * 16 + quad * 4;   // local token 0..255
            f16x4 p = { (_Float16)(acc[Ah][i][pass][jn][0] + bb),
                        (_Float16)(acc[Ah][i][pass][jn][1] + bb),
                        (_Float16)(acc[Ah][i][pass][jn][2] + bb),
                        (_Float16)(acc[Ah][i][pass][jn][3] + bb) };
            *(f16x4*)(ldsT + fl * 264 + rl) = p;
          }
      }
      FENCE;
      __builtin_amdgcn_s_barrier();
      FENCE;
#pragma unroll
      for (int p = 0; p < 8; ++p) {
        int f = p * 16 + (tid >> 5);            // 0..127
        int cc = tid & 31;                      // 32 x 8 f16 = 256 tokens
        f16x8 v = *(const f16x8*)(ldsT + f * 264 + cc * 8);
        *(f16x8*)(VtB + (long)(tn + pass * 128 + f) * N_ + cc * 8) = v;
      }
    }
  }
}

// ---------------------------------------------------------------- scores: P' = exp(QK^T*delta)
// 256x256 tile, 256 blocks (exactly 1/CU). 2-pass LDS bounce for coalesced stores.
__global__ __launch_bounds__(512, 2) void k_scores(const f16* __restrict__ Qf,
                                                   const f16* __restrict__ Kf,
                                                   f16* __restrict__ S,
                                                   float* __restrict__ rowsum) {
  __shared__ __align__(16) char lds[131072];
  int fid = blockIdx.x;
  int xcd = fid & 7, k = fid >> 3;
  int lin = xcd * 32 + k;
  int b = lin >> 6;
  int t = lin & 63;
  int rowt = t & 7, colt = t >> 3;
  int tm = rowt * 256, tn = colt * 256;
  f32x4 acc[2][4][2][2];
#pragma unroll
  for (int Ah = 0; Ah < 2; ++Ah)
#pragma unroll
    for (int i = 0; i < 4; ++i)
#pragma unroll
      for (int Bh = 0; Bh < 2; ++Bh)
#pragma unroll
        for (int jn = 0; jn < 2; ++jn) acc[Ah][i][Bh][jn] = (f32x4){0.f, 0.f, 0.f, 0.f};
  gemm256((const char*)(Qf + (long)b * N_ * D_ + (long)tm * D_), D_ * 2,
          (const char*)(Kf + (long)b * N_ * D_ + (long)tn * D_), D_ * 2,
          D_ / 64, lds, acc);
  const int tid = threadIdx.x;
  const int lane = tid & 63, wave = tid >> 6;
  const int wm = wave >> 2, wn = wave & 3;
  const int quad = lane >> 4, l16 = lane & 15;
  f16* Sb = S + (long)b * N_ * N_;
  const float delta = 0.03125f;               // 1/sqrt(1024); exp <= ~e^6, f16-safe
  f16* ldsS = (f16*)lds;                      // 256 x 136 f16 per pass
  float rsum[2][4][4];
#pragma unroll
  for (int Ah = 0; Ah < 2; ++Ah)
#pragma unroll
    for (int i = 0; i < 4; ++i)
#pragma unroll
      for (int r = 0; r < 4; ++r) rsum[Ah][i][r] = 0.f;
#pragma unroll
  for (int Bh = 0; Bh < 2; ++Bh) {            // pass over col-halves
    FENCE;
    __builtin_amdgcn_s_barrier();
    FENCE;
#pragma unroll
    for (int Ah = 0; Ah < 2; ++Ah)
#pragma unroll
      for (int i = 0; i < 4; ++i) {
        int rloc = Ah * 128 + wm * 64 + i * 16 + quad * 4;
#pragma unroll
        for (int jn = 0; jn < 2; ++jn) {
          int col = wn * 32 + jn * 16 + l16;
#pragma unroll
          for (int r = 0; r < 4; ++r) {
            float e = __expf(acc[Ah][i][Bh][jn][r] * delta);
            rsum[Ah][i][r] += e;
            ldsS[(rloc + r) * 136 + col] = (_Float16)e;
          }
        }
      }
    FENCE;
    __builtin_amdgcn_s_barrier();
    FENCE;
#pragma unroll
    for (int p = 0; p < 8; ++p) {
      int row = p * 32 + (tid >> 4);
      int cc = tid & 15;
      f16x8 v = *(const f16x8*)(ldsS + row * 136 + cc * 8);
      *(f16x8*)(Sb + (long)(tm + row) * N_ + tn + Bh * 128 + cc * 8) = v;
    }
  }
#pragma unroll
  for (int m = 1; m < 16; m <<= 1)
#pragma unroll
    for (int Ah = 0; Ah < 2; ++Ah)
#pragma unroll
      for (int i = 0; i < 4; ++i)
#pragma unroll
        for (int r = 0; r < 4; ++r) rsum[Ah][i][r] += __shfl_xor(rsum[Ah][i][r], m);
  if (l16 == 0) {
    float* rs = rowsum + (long)b * N_ + tm;
#pragma unroll
    for (int Ah = 0; Ah < 2; ++Ah)
#pragma unroll
      for (int i = 0; i < 4; ++i)
#pragma unroll
        for (int r = 0; r < 4; ++r)
          atomicAdd(rs + Ah * 128 + wm * 64 + i * 16 + quad * 4 + r, rsum[Ah][i][r]);
  }
}

// ---------------------------------------------------------------- O = (P' V)/rowsum * gamma + x
// 128x256 tiles -> 16x4 per batch = 256 blocks (1/CU, one round). Deep-phase GEMM.
__global__ __launch_bounds__(512, 2) void k_out(const f16* __restrict__ P,
                                                const f16* __restrict__ Vt,
                                                const f16* __restrict__ xf,
                                                const float* __restrict__ gamma,
                                                const float* __restrict__ rowsum,
                                                float* __restrict__ out) {
  __shared__ __align__(16) char lds[98304];
  int fid = blockIdx.x;
  int xcd = fid & 7, kq = fid >> 3;
  int lin = xcd * 32 + kq;                  // 0..255
  int b = lin >> 6;                         // 0..3
  int t = lin & 63;
  int rowt = t >> 2, colt = t & 3;          // colt fast: P row-panel shared by 4 blocks
  int tm = rowt * 128, tn = colt * 256;
  f32x4 acc[4][2][2];
#pragma unroll
  for (int i = 0; i < 4; ++i)
#pragma unroll
    for (int Bh = 0; Bh < 2; ++Bh)
#pragma unroll
      for (int jn = 0; jn < 2; ++jn) acc[i][Bh][jn] = (f32x4){0.f, 0.f, 0.f, 0.f};
  gemm_d128((const char*)(P + (long)b * N_ * N_ + (long)tm * N_), N_ * 2,
            (const char*)(Vt + (long)b * D_ * N_ + (long)tn * N_), N_ * 2,
            N_ / 64, lds, acc);
  const int tid = threadIdx.x;
  const int lane = tid & 63, wave = tid >> 6;
  const int wm = wave >> 2, wn = wave & 3;
  const int quad = lane >> 4, l16 = lane & 15;
  float g = gamma[0];
  float inv[4][4];
#pragma unroll
  for (int i = 0; i < 4; ++i)
#pragma unroll
    for (int r = 0; r < 4; ++r)
      inv[i][r] = g / rowsum[(long)b * N_ + tm + wm * 64 + i * 16 + quad * 4 + r];
#pragma unroll
  for (int Bh = 0; Bh < 2; ++Bh)
#pragma unroll
    for (int jn = 0; jn < 2; ++jn) {
      int col = tn + Bh * 128 + wn * 32 + jn * 16 + l16;
#pragma unroll
      for (int i = 0; i < 4; ++i) {
        int rbase = tm + wm * 64 + i * 16 + quad * 4;
#pragma unroll
        for (int r = 0; r < 4; ++r) {
          long idx = (long)b * N_ * D_ + (long)(rbase + r) * D_ + col;
          out[idx] = acc[i][Bh][jn][r] * inv[i][r] + (float)xf[idx];
        }
      }
    }
}

// ---------------------------------------------------------------- launch
extern "C" void kernel_launch(void* const* d_in, const int* in_sizes, int n_in,
                              void* d_out, int out_size, void* d_ws, size_t ws_size,
                              hipStream_t stream) {
  const float* x  = (const float*)d_in[0];
  const float* Wq = (const float*)d_in[1];
  const float* bq = (const float*)d_in[2];
  const float* Wk = (const float*)d_in[3];
  const float* bk = (const float*)d_in[4];
  const float* Wv = (const float*)d_in[5];
  const float* bv = (const float*)d_in[6];
  const float* gamma = (const float*)d_in[7];
  float* out = (float*)d_out;
  char* ws = (char*)d_ws;

  // ws layout: Xb stays ALIVE through k_out (x re-read as f16).
  // S overlays only the dead W buffers. Peak 96 MB (+32 KB rowsum).
  f16* Qb  = (f16*)(ws);                      // 0..16 MB
  f16* Kb  = (f16*)(ws + (16u << 20));        // 16..32 MB
  f16* Vt  = (f16*)(ws + (32u << 20));        // 32..48 MB (written directly by k_qkv)
  f16* Xb  = (f16*)(ws + (48u << 20));        // 48..64 MB (alive through k_out)
  f16* Wqb = (f16*)(ws + (64u << 20));        // 64..66 MB (dead after k_qkv)
  f16* Wkb = (f16*)(ws + (66u << 20));        // 66..68 MB
  f16* Wvb = (f16*)(ws + (68u << 20));        // 68..70 MB
  f16* S   = (f16*)(ws + (64u << 20));        // 64..96 MB, overlays dead W's
  float* rowsum = (float*)(ws + (96u << 20)); // 32 KB

  k_cast_all<<<11296, 256, 0, stream>>>((const float4*)x, (const float4*)Wq,
                                        (const float4*)Wk, (const float4*)Wv,
                                        (f16x4*)Xb, (f16x4*)Wqb, (f16x4*)Wkb, (f16x4*)Wvb,
                                        rowsum);
  k_qkv<<<384, 512, 0, stream>>>(Xb, Wqb, Wkb, Wvb, bq, bk, bv, Qb, Kb, Vt);
  k_scores<<<256, 512, 0, stream>>>(Qb, Kb, S, rowsum);
  k_out<<<256, 512, 0, stream>>>(S, Vt, Xb, gamma, rowsum, out);
}

// Round 8
// 223.711 us; speedup vs baseline: 1.5473x; 1.5473x over previous
//
#include <hip/hip_runtime.h>

typedef _Float16 f16;
typedef __attribute__((ext_vector_type(4))) _Float16 f16x4;
typedef __attribute__((ext_vector_type(8))) _Float16 f16x8;
typedef __attribute__((ext_vector_type(4))) float f32x4;

#define B_ 4
#define N_ 2048
#define D_ 1024

#define FENCE asm volatile("" ::: "memory")

// ---------------------------------------------------------------- cast fp32->fp16 + rowsum zeroing
__global__ __launch_bounds__(256) void k_cast_all(const float4* __restrict__ x,
                                                  const float4* __restrict__ wq,
                                                  const float4* __restrict__ wk,
                                                  const float4* __restrict__ wv,
                                                  f16x4* __restrict__ xo,
                                                  f16x4* __restrict__ wqo,
                                                  f16x4* __restrict__ wko,
                                                  f16x4* __restrict__ wvo,
                                                  float* __restrict__ rowsum) {
  int b = blockIdx.x;
  if (b >= 11264) {                      // 32 blocks zero the 8192-float rowsum
    rowsum[(b - 11264) * 256 + threadIdx.x] = 0.f;
    return;
  }
  const float4* in;
  f16x4* out;
  int idx;
  if (b < 8192)       { in = x;  out = xo;  idx = b * 256 + threadIdx.x; }
  else if (b < 9216)  { in = wq; out = wqo; idx = (b - 8192) * 256 + threadIdx.x; }
  else if (b < 10240) { in = wk; out = wko; idx = (b - 9216) * 256 + threadIdx.x; }
  else                { in = wv; out = wvo; idx = (b - 10240) * 256 + threadIdx.x; }
  float4 v = in[idx];
  f16x4 o = { (_Float16)v.x, (_Float16)v.y, (_Float16)v.z, (_Float16)v.w };
  out[idx] = o;
}

// ---------------------------------------------------------------- staging (proven-clean geometry)
// Half-tile = 128 rows x 128 B (BK=64 f16). 16B chunks XOR-swizzled by (row&7)
// on the GLOBAL source (LDS dest stays linear per global_load_lds constraint);
// reads apply the same XOR -> both-sides involution. 2 loads/thread.
__device__ __forceinline__ void stage_half(const char* g0, int ldB, int kByte,
                                           char* slot, int tid) {
#pragma unroll
  for (int r = 0; r < 2; ++r) {
    int lin = r * 8192 + tid * 16;
    int row = lin >> 7;
    int lch = ((lin >> 4) & 7) ^ (row & 7);
    const char* g = g0 + (long)row * ldB + kByte + lch * 16;
    char* l = slot + r * 8192 + ((tid >> 6) << 10);   // wave-uniform base; HW adds lane*16
    __builtin_amdgcn_global_load_lds(
        (const __attribute__((address_space(1))) unsigned int*)g,
        (__attribute__((address_space(3))) unsigned int*)l, 16, 0, 0);
  }
}

// ---------------------------------------------------------------- fragment read / MFMA macros
#define RD_A(dst, base)                                                          \
  _Pragma("unroll") for (int i_ = 0; i_ < 4; ++i_) {                             \
    int rA_ = wm * 64 + i_ * 16 + l16;                                           \
    _Pragma("unroll") for (int k_ = 0; k_ < 2; ++k_)                             \
      dst[i_][k_] = *(const f16x8*)((base) + rA_ * 128 +                         \
                                    ((((k_ << 2) | quad) ^ l7) << 4));           \
  }
#define RD_B(dst, base)                                                          \
  _Pragma("unroll") for (int j_ = 0; j_ < 2; ++j_) {                             \
    int rB_ = wn * 32 + j_ * 16 + l16;                                           \
    _Pragma("unroll") for (int k_ = 0; k_ < 2; ++k_)                             \
      dst[j_][k_] = *(const f16x8*)((base) + rB_ * 128 +                         \
                                    ((((k_ << 2) | quad) ^ l7) << 4));           \
  }
#define MFMA8(Av, Bv, BH)                                                        \
  __builtin_amdgcn_s_setprio(1);                                                 \
  _Pragma("unroll") for (int i_ = 0; i_ < 4; ++i_)                               \
  _Pragma("unroll") for (int j_ = 0; j_ < 2; ++j_)                               \
  _Pragma("unroll") for (int k_ = 0; k_ < 2; ++k_)                               \
    acc[i_][BH][j_] = __builtin_amdgcn_mfma_f32_16x16x32_f16(                    \
        Av[i_][k_], Bv[j_][k_], acc[i_][BH][j_], 0, 0, 0);                       \
  __builtin_amdgcn_s_setprio(0);
#define MFMA16(Av, Bv, AH, BH)                                                   \
  __builtin_amdgcn_s_setprio(1);                                                 \
  _Pragma("unroll") for (int i_ = 0; i_ < 4; ++i_)                               \
  _Pragma("unroll") for (int j_ = 0; j_ < 2; ++j_)                               \
  _Pragma("unroll") for (int k_ = 0; k_ < 2; ++k_)                               \
    acc[AH][i_][BH][j_] = __builtin_amdgcn_mfma_f32_16x16x32_f16(                \
        Av[i_][k_], Bv[j_][k_], acc[AH][i_][BH][j_], 0, 0, 0);                   \
  __builtin_amdgcn_s_setprio(0);

// ---------------------------------------------------------------- 256x256 reads-ahead NT GEMM (v2)
// MEASURED R6 (part of 235.6 total) — do not modify without an A/B.
// 8 waves, wave tile 128x64. Quadrant walk (0,0),(1,0),(0,1),(1,1), reads one
// phase ahead, staging 2 halves at P0 / 2 at P2, waits vmcnt 6/4/4/- per tile.
__device__ __forceinline__ void gemm256(const char* gA, int ldaB,
                                        const char* gB, int ldbB,
                                        int nK, char* lds, f32x4 acc[2][4][2][2]) {
  const int tid = threadIdx.x;
  const int lane = tid & 63, wave = tid >> 6;
  const int wm = wave >> 2, wn = wave & 3;
  const int quad = lane >> 4, l16 = lane & 15;
  const int l7 = l16 & 7;
  const char* gA1 = gA + (long)128 * ldaB;
  const char* gB1 = gB + (long)128 * ldbB;
  char* Abuf = lds;            // 2 x 32 KB (half h at +h*16384)
  char* Bbuf = lds + 65536;    // 2 x 32 KB
  f16x8 a0[4][2], a1[4][2], bX[2][2], bY[2][2];
  // prologue: stage tile0's 4 halves (8 loads); read A0,B0
  stage_half(gA,  ldaB, 0, Abuf, tid);
  stage_half(gB,  ldbB, 0, Bbuf, tid);
  stage_half(gA1, ldaB, 0, Abuf + 16384, tid);
  stage_half(gB1, ldbB, 0, Bbuf + 16384, tid);
  asm volatile("s_waitcnt vmcnt(4)" ::: "memory");
  __builtin_amdgcn_s_barrier(); FENCE;
  RD_A(a0, Abuf); RD_B(bX, Bbuf);
  for (int t = 0; t < nK; ++t) {
    const int c = t & 1;
    char* Ac = Abuf + c * 32768;
    char* Bc = Bbuf + c * 32768;
    char* An = Abuf + (c ^ 1) * 32768;
    char* Bn = Bbuf + (c ^ 1) * 32768;
    const bool st = (t + 1 < nK);
    const int kB = (t + 1) << 7;
    // P0: quadrant (0,0); read a1 = A1(t)
    if (st) { stage_half(gA, ldaB, kB, An, tid); stage_half(gB, ldbB, kB, Bn, tid); }
    if (st) asm volatile("s_waitcnt vmcnt(6)" ::: "memory");
    else    asm volatile("s_waitcnt vmcnt(2)" ::: "memory");
    __builtin_amdgcn_s_barrier(); FENCE;
    RD_A(a1, Ac + 16384);
    MFMA16(a0, bX, 0, 0);
    // P1: (1,0); read bY = B1(t)
    if (st) asm volatile("s_waitcnt vmcnt(4)" ::: "memory");
    else    asm volatile("s_waitcnt vmcnt(0)" ::: "memory");
    __builtin_amdgcn_s_barrier(); FENCE;
    RD_B(bY, Bc + 16384);
    MFMA16(a1, bX, 1, 0);
    // P2: (0,1); read bX = B0(t+1)
    if (st) { stage_half(gA1, ldaB, kB, An + 16384, tid); stage_half(gB1, ldbB, kB, Bn + 16384, tid); }
    if (st) asm volatile("s_waitcnt vmcnt(4)" ::: "memory");
    __builtin_amdgcn_s_barrier(); FENCE;
    if (st) RD_B(bX, Bn);
    MFMA16(a0, bY, 0, 1);
    // P3: (1,1); read a0 = A0(t+1) (landed: retired at P2's wait)
    __builtin_amdgcn_s_barrier(); FENCE;
    if (st) RD_A(a0, An);
    MFMA16(a1, bY, 1, 1);
  }
  asm volatile("s_waitcnt vmcnt(0)" ::: "memory");
  __builtin_amdgcn_s_barrier();
  FENCE;
}

// ---------------------------------------------------------------- 128x256 DEEP-phase NT GEMM
// MEASURED R5 (k_qkv 60.8 µs @768 blocks) — do not modify without an A/B.
// 8 waves, wave 64x64; reads-one-phase-ahead, dbuf 48 KB x2.
#define D128_TILE(AC, B0C, AN, B0N, q) {                                         \
  char* Sc = lds + (q) * 49152;                                                  \
  char* Sn = lds + ((q) ^ 1) * 49152;                                            \
  const int kB = (t + 1) << 7;                                                   \
  stage_half(gA, ldaB, kB, Sn, tid);                                             \
  stage_half(gB, ldbB, kB, Sn + 16384, tid);                                     \
  asm volatile("s_waitcnt vmcnt(4)" ::: "memory");                               \
  __builtin_amdgcn_s_barrier(); FENCE;                                           \
  RD_B(b1, Sc + 32768);                                                          \
  MFMA8(AC, B0C, 0);                                                             \
  stage_half(gB1, ldbB, kB, Sn + 32768, tid);                                    \
  asm volatile("s_waitcnt vmcnt(2)" ::: "memory");                               \
  __builtin_amdgcn_s_barrier(); FENCE;                                           \
  RD_A(AN, Sn); RD_B(B0N, Sn + 16384);                                           \
  MFMA8(AC, b1, 1);                                                              \
}
#define D128_TAIL(AC, B0C, q) {                                                  \
  char* Sc = lds + (q) * 49152;                                                  \
  asm volatile("s_waitcnt vmcnt(0)" ::: "memory");                               \
  __builtin_amdgcn_s_barrier(); FENCE;                                           \
  RD_B(b1, Sc + 32768);                                                          \
  MFMA8(AC, B0C, 0);                                                             \
  MFMA8(AC, b1, 1);                                                              \
}

__device__ __forceinline__ void gemm_d128(const char* gA, int ldaB,
                                          const char* gB, int ldbB,
                                          int nK, char* lds, f32x4 acc[4][2][2]) {
  const int tid = threadIdx.x;
  const int lane = tid & 63, wave = tid >> 6;
  const int wm = wave >> 2, wn = wave & 3;
  const int quad = lane >> 4, l16 = lane & 15;
  const int l7 = l16 & 7;
  const char* gB1 = gB + (long)128 * ldbB;
  f16x8 aX[4][2], aY[4][2], b0X[2][2], b0Y[2][2], b1[2][2];
  stage_half(gA,  ldaB, 0, lds, tid);
  stage_half(gB,  ldbB, 0, lds + 16384, tid);
  stage_half(gB1, ldbB, 0, lds + 32768, tid);
  asm volatile("s_waitcnt vmcnt(2)" ::: "memory");   // A,B0 landed; B1 in flight
  __builtin_amdgcn_s_barrier(); FENCE;
  RD_A(aX, lds); RD_B(b0X, lds + 16384);
  for (int tb = 0; tb < nK - 2; tb += 2) {
    { const int t = tb;     D128_TILE(aX, b0X, aY, b0Y, 0) }
    { const int t = tb + 1; D128_TILE(aY, b0Y, aX, b0X, 1) }
  }
  { const int t = nK - 2;   D128_TILE(aX, b0X, aY, b0Y, 0) }
  D128_TAIL(aY, b0Y, 1)
  __builtin_amdgcn_s_barrier(); FENCE;   // all waves' frag reads done -> LDS reusable
}

// ---------------------------------------------------------------- fused QKV projection (+V transpose)
// R5 config (measured 60.8 µs): wide GEMM [8192, 3072] in 128x256 tiles
// -> 768 blocks = 3 exact rounds (no tail).
__global__ __launch_bounds__(512, 2) void k_qkv(const f16* __restrict__ X,
                                                const f16* __restrict__ Wq,
                                                const f16* __restrict__ Wk,
                                                const f16* __restrict__ Wv,
                                                const float* __restrict__ bq,
                                                const float* __restrict__ bk,
                                                const float* __restrict__ bv,
                                                f16* __restrict__ Q, f16* __restrict__ Ko,
                                                f16* __restrict__ Vt) {
  __shared__ __align__(16) char lds[98304];
  int fid = blockIdx.x;
  int xcd = fid & 7, k = fid >> 3;          // k in [0,96)
  int rowt = xcd * 8 + (k & 7);             // 0..63: 8-row-tile band per XCD
  int colt = k >> 3;                        // 0..11
  int tm = rowt * 128;
  int w = colt >> 2;                        // 0:Q 1:K 2:V
  int tn = (colt & 3) * 256;
  const f16* Wsel = (w == 0) ? Wq : (w == 1) ? Wk : Wv;
  f32x4 acc[4][2][2];
#pragma unroll
  for (int i = 0; i < 4; ++i)
#pragma unroll
    for (int Bh = 0; Bh < 2; ++Bh)
#pragma unroll
      for (int jn = 0; jn < 2; ++jn) acc[i][Bh][jn] = (f32x4){0.f, 0.f, 0.f, 0.f};
  gemm_d128((const char*)(X + (long)tm * D_), D_ * 2,
            (const char*)(Wsel + (long)tn * D_), D_ * 2, D_ / 64, lds, acc);
  const int tid = threadIdx.x;
  const int lane = tid & 63, wave = tid >> 6;
  const int wm = wave >> 2, wn = wave & 3;
  const int quad = lane >> 4, l16 = lane & 15;
  if (w < 2) {
    const float* bias = w ? bk : bq;
    f16* outp = w ? Ko : Q;
#pragma unroll
    for (int Bh = 0; Bh < 2; ++Bh)
#pragma unroll
      for (int jn = 0; jn < 2; ++jn) {
        int col = tn + Bh * 128 + wn * 32 + jn * 16 + l16;
        float bb = bias[col];
#pragma unroll
        for (int i = 0; i < 4; ++i) {
          int rbase = tm + wm * 64 + i * 16 + quad * 4;
#pragma unroll
          for (int r = 0; r < 4; ++r)
            outp[(long)(rbase + r) * D_ + col] = (_Float16)(acc[i][Bh][jn][r] + bb);
        }
      }
  } else {
    // V: transpose through LDS (256 feats x 136-f16 pitch = 69.6 KB), coalesced Vt stores
    int bidx = tm >> 11, ntok = tm & 2047;
    f16* VtB = Vt + (long)bidx * D_ * N_ + ntok;
    f16* ldsT = (f16*)lds;
#pragma unroll
    for (int Bh = 0; Bh < 2; ++Bh)
#pragma unroll
      for (int jn = 0; jn < 2; ++jn) {
        int fl = Bh * 128 + wn * 32 + jn * 16 + l16;   // local feature 0..255
        float bb = bv[tn + fl];
#pragma unroll
        for (int i = 0; i < 4; ++i) {
          int rl = wm * 64 + i * 16 + quad * 4;        // local token 0..127
          f16x4 p = { (_Float16)(acc[i][Bh][jn][0] + bb), (_Float16)(acc[i][Bh][jn][1] + bb),
                      (_Float16)(acc[i][Bh][jn][2] + bb), (_Float16)(acc[i][Bh][jn][3] + bb) };
          *(f16x4*)(ldsT + fl * 136 + rl) = p;
        }
      }
    FENCE;
    __builtin_amdgcn_s_barrier();
    FENCE;
#pragma unroll
    for (int p = 0; p < 8; ++p) {
      int f = p * 32 + (tid >> 4);            // 0..255
      int cc = tid & 15;                      // 16 x 8 f16 = 128 tokens
      f16x8 v = *(const f16x8*)(ldsT + f * 136 + cc * 8);
      *(f16x8*)(VtB + (long)(tn + f) * N_ + cc * 8) = v;
    }
  }
}

// ---------------------------------------------------------------- scores: P' = exp(QK^T*delta)
// R6 config (measured): 256x256 tile, gemm256 v2, 256 blocks (1/CU).
__global__ __launch_bounds__(512, 2) void k_scores(const f16* __restrict__ Qf,
                                                   const f16* __restrict__ Kf,
                                                   f16* __restrict__ S,
                                                   float* __restrict__ rowsum) {
  __shared__ __align__(16) char lds[131072];
  int fid = blockIdx.x;
  int xcd = fid & 7, k = fid >> 3;
  int lin = xcd * 32 + k;
  int b = lin >> 6;
  int t = lin & 63;
  int rowt = t & 7, colt = t >> 3;
  int tm = rowt * 256, tn = colt * 256;
  f32x4 acc[2][4][2][2];
#pragma unroll
  for (int Ah = 0; Ah < 2; ++Ah)
#pragma unroll
    for (int i = 0; i < 4; ++i)
#pragma unroll
      for (int Bh = 0; Bh < 2; ++Bh)
#pragma unroll
        for (int jn = 0; jn < 2; ++jn) acc[Ah][i][Bh][jn] = (f32x4){0.f, 0.f, 0.f, 0.f};
  gemm256((const char*)(Qf + (long)b * N_ * D_ + (long)tm * D_), D_ * 2,
          (const char*)(Kf + (long)b * N_ * D_ + (long)tn * D_), D_ * 2,
          D_ / 64, lds, acc);
  const int tid = threadIdx.x;
  const int lane = tid & 63, wave = tid >> 6;
  const int wm = wave >> 2, wn = wave & 3;
  const int quad = lane >> 4, l16 = lane & 15;
  f16* Sb = S + (long)b * N_ * N_;
  const float delta = 0.03125f;               // 1/sqrt(1024); exp <= ~e^6, f16-safe
  f16* ldsS = (f16*)lds;                      // 256 x 136 f16 per pass
  float rsum[2][4][4];
#pragma unroll
  for (int Ah = 0; Ah < 2; ++Ah)
#pragma unroll
    for (int i = 0; i < 4; ++i)
#pragma unroll
      for (int r = 0; r < 4; ++r) rsum[Ah][i][r] = 0.f;
#pragma unroll
  for (int Bh = 0; Bh < 2; ++Bh) {            // pass over col-halves
    FENCE;
    __builtin_amdgcn_s_barrier();
    FENCE;
#pragma unroll
    for (int Ah = 0; Ah < 2; ++Ah)
#pragma unroll
      for (int i = 0; i < 4; ++i) {
        int rloc = Ah * 128 + wm * 64 + i * 16 + quad * 4;
#pragma unroll
        for (int jn = 0; jn < 2; ++jn) {
          int col = wn * 32 + jn * 16 + l16;
#pragma unroll
          for (int r = 0; r < 4; ++r) {
            float e = __expf(acc[Ah][i][Bh][jn][r] * delta);
            rsum[Ah][i][r] += e;
            ldsS[(rloc + r) * 136 + col] = (_Float16)e;
          }
        }
      }
    FENCE;
    __builtin_amdgcn_s_barrier();
    FENCE;
#pragma unroll
    for (int p = 0; p < 8; ++p) {
      int row = p * 32 + (tid >> 4);
      int cc = tid & 15;
      f16x8 v = *(const f16x8*)(ldsS + row * 136 + cc * 8);
      *(f16x8*)(Sb + (long)(tm + row) * N_ + tn + Bh * 128 + cc * 8) = v;
    }
  }
#pragma unroll
  for (int m = 1; m < 16; m <<= 1)
#pragma unroll
    for (int Ah = 0; Ah < 2; ++Ah)
#pragma unroll
      for (int i = 0; i < 4; ++i)
#pragma unroll
        for (int r = 0; r < 4; ++r) rsum[Ah][i][r] += __shfl_xor(rsum[Ah][i][r], m);
  if (l16 == 0) {
    float* rs = rowsum + (long)b * N_ + tm;
#pragma unroll
    for (int Ah = 0; Ah < 2; ++Ah)
#pragma unroll
      for (int i = 0; i < 4; ++i)
#pragma unroll
        for (int r = 0; r < 4; ++r)
          atomicAdd(rs + Ah * 128 + wm * 64 + i * 16 + quad * 4 + r, rsum[Ah][i][r]);
  }
}

// ---------------------------------------------------------------- O = (P' V)/rowsum * gamma + x
// R5/R6 config (measured): 128x256 tiles -> 256 blocks (1/CU), gemm_d128.
__global__ __launch_bounds__(512, 2) void k_out(const f16* __restrict__ P,
                                                const f16* __restrict__ Vt,
                                                const f16* __restrict__ xf,
                                                const float* __restrict__ gamma,
                                                const float* __restrict__ rowsum,
                                                float* __restrict__ out) {
  __shared__ __align__(16) char lds[98304];
  int fid = blockIdx.x;
  int xcd = fid & 7, kq = fid >> 3;
  int lin = xcd * 32 + kq;                  // 0..255
  int b = lin >> 6;                         // 0..3
  int t = lin & 63;
  int rowt = t >> 2, colt = t & 3;          // colt fast: P row-panel shared by 4 blocks
  int tm = rowt * 128, tn = colt * 256;
  f32x4 acc[4][2][2];
#pragma unroll
  for (int i = 0; i < 4; ++i)
#pragma unroll
    for (int Bh = 0; Bh < 2; ++Bh)
#pragma unroll
      for (int jn = 0; jn < 2; ++jn) acc[i][Bh][jn] = (f32x4){0.f, 0.f, 0.f, 0.f};
  gemm_d128((const char*)(P + (long)b * N_ * N_ + (long)tm * N_), N_ * 2,
            (const char*)(Vt + (long)b * D_ * N_ + (long)tn * N_), N_ * 2,
            N_ / 64, lds, acc);
  const int tid = threadIdx.x;
  const int lane = tid & 63, wave = tid >> 6;
  const int wm = wave >> 2, wn = wave & 3;
  const int quad = lane >> 4, l16 = lane & 15;
  float g = gamma[0];
  float inv[4][4];
#pragma unroll
  for (int i = 0; i < 4; ++i)
#pragma unroll
    for (int r = 0; r < 4; ++r)
      inv[i][r] = g / rowsum[(long)b * N_ + tm + wm * 64 + i * 16 + quad * 4 + r];
#pragma unroll
  for (int Bh = 0; Bh < 2; ++Bh)
#pragma unroll
    for (int jn = 0; jn < 2; ++jn) {
      int col = tn + Bh * 128 + wn * 32 + jn * 16 + l16;
#pragma unroll
      for (int i = 0; i < 4; ++i) {
        int rbase = tm + wm * 64 + i * 16 + quad * 4;
#pragma unroll
        for (int r = 0; r < 4; ++r) {
          long idx = (long)b * N_ * D_ + (long)(rbase + r) * D_ + col;
          out[idx] = acc[i][Bh][jn][r] * inv[i][r] + (float)xf[idx];
        }
      }
    }
}

// ---------------------------------------------------------------- launch
extern "C" void kernel_launch(void* const* d_in, const int* in_sizes, int n_in,
                              void* d_out, int out_size, void* d_ws, size_t ws_size,
                              hipStream_t stream) {
  const float* x  = (const float*)d_in[0];
  const float* Wq = (const float*)d_in[1];
  const float* bq = (const float*)d_in[2];
  const float* Wk = (const float*)d_in[3];
  const float* bk = (const float*)d_in[4];
  const float* Wv = (const float*)d_in[5];
  const float* bv = (const float*)d_in[6];
  const float* gamma = (const float*)d_in[7];
  float* out = (float*)d_out;
  char* ws = (char*)d_ws;

  // ws layout: Xb stays ALIVE through k_out (x re-read as f16).
  // S overlays only the dead W buffers. Peak 96 MB (+32 KB rowsum).
  f16* Qb  = (f16*)(ws);                      // 0..16 MB
  f16* Kb  = (f16*)(ws + (16u << 20));        // 16..32 MB
  f16* Vt  = (f16*)(ws + (32u << 20));        // 32..48 MB (written directly by k_qkv)
  f16* Xb  = (f16*)(ws + (48u << 20));        // 48..64 MB (alive through k_out)
  f16* Wqb = (f16*)(ws + (64u << 20));        // 64..66 MB (dead after k_qkv)
  f16* Wkb = (f16*)(ws + (66u << 20));        // 66..68 MB
  f16* Wvb = (f16*)(ws + (68u << 20));        // 68..70 MB
  f16* S   = (f16*)(ws + (64u << 20));        // 64..96 MB, overlays dead W's
  float* rowsum = (float*)(ws + (96u << 20)); // 32 KB

  k_cast_all<<<11296, 256, 0, stream>>>((const float4*)x, (const float4*)Wq,
                                        (const float4*)Wk, (const float4*)Wv,
                                        (f16x4*)Xb, (f16x4*)Wqb, (f16x4*)Wkb, (f16x4*)Wvb,
                                        rowsum);
  k_qkv<<<768, 512, 0, stream>>>(Xb, Wqb, Wkb, Wvb, bq, bk, bv, Qb, Kb, Vt);
  k_scores<<<256, 512, 0, stream>>>(Qb, Kb, S, rowsum);
  k_out<<<256, 512, 0, stream>>>(S, Vt, Xb, gamma, rowsum, out);
}